// Round 7
// baseline (672.761 us; speedup 1.0000x reference)
//
#include <hip/hip_runtime.h>

#define NN     50000
#define NE     20000
#define NNZV   800000
#define FD     256
#define EPSV   1e-5f
#define MPAD   20032     // NE rounded up to 64 for GEMM tiling
#define NCPY   128       // histogram copies (= hist blocks)
#define EPB    (NNZV / NCPY)         // 6250 entries per hist block
#define HEC    (NE / 2)              // 10000 packed u32 cells (edge)
#define HNC    (NN / 2)              // 25000 packed u32 cells (node)
#define HTC    (HEC + HNC)           // 35000 cells = 140 KB LDS
#define BE     ((NE + 255) / 256)    // 79 scan blocks (edge side)
#define BN     ((NN + 255) / 256)    // 196 scan blocks (node side)

typedef __attribute__((ext_vector_type(8))) __bf16 bf16x8;
typedef __attribute__((ext_vector_type(4))) __bf16 bf16x4;
typedef __attribute__((ext_vector_type(4))) float f32x4;

__device__ __forceinline__ float b2f(unsigned short u) {
  union { unsigned int i; float f; } z; z.i = ((unsigned)u) << 16; return z.f;
}

// ---- CSR construction: LDS histogram, zero global atomics -------------------

__global__ __launch_bounds__(256) void
hg_histlds(const int* __restrict__ nidx, const int* __restrict__ eidx,
           unsigned* __restrict__ cntc,
           unsigned short* __restrict__ rank_e16, unsigned short* __restrict__ rank_n16) {
  __shared__ unsigned hist[HTC];   // 140 KB
  int b = blockIdx.x, t = threadIdx.x;
  for (int j = t; j < HTC; j += 256) hist[j] = 0;
  __syncthreads();
  int i0 = b * EPB;
  for (int i = i0 + t; i < i0 + EPB; i += 256) {
    int e = eidx[i];
    int n = nidx[i];
    unsigned se = (e & 1) * 16;
    unsigned sn = (n & 1) * 16;
    unsigned oe = atomicAdd(&hist[e >> 1], 1u << se);
    unsigned on = atomicAdd(&hist[HEC + (n >> 1)], 1u << sn);
    rank_e16[i] = (unsigned short)((oe >> se) & 0xffffu);
    rank_n16[i] = (unsigned short)((on >> sn) & 0xffffu);
  }
  __syncthreads();
  unsigned* dst = cntc + (size_t)b * HTC;
  for (int j = t; j < HTC; j += 256) dst[j] = hist[j];
}

// per-key exclusive prefix over copies (in place, packed) + per-key totals
__global__ void hg_colreduce(unsigned* __restrict__ cntc,
                             int* __restrict__ total_e, int* __restrict__ total_n) {
  int j = blockIdx.x * 256 + threadIdx.x;
  if (j >= HTC) return;
  unsigned run = 0;
#pragma unroll 4
  for (int c = 0; c < NCPY; ++c) {
    unsigned v = cntc[(size_t)c * HTC + j];
    cntc[(size_t)c * HTC + j] = run;
    run += v;                      // packed u16 pair add, no cross-carry
  }
  if (j < HEC) {
    total_e[2 * j]     = run & 0xffffu;
    total_e[2 * j + 1] = run >> 16;
  } else {
    int k = j - HEC;
    total_n[2 * k]     = run & 0xffffu;
    total_n[2 * k + 1] = run >> 16;
  }
}

// ---- 3-phase exclusive scan over total_e (BE blocks) and total_n (BN blocks)

__global__ void hg_scan1(const int* __restrict__ total_e, const int* __restrict__ total_n,
                         int* __restrict__ part) {
  __shared__ int lds[256];
  int b = blockIdx.x;
  const int* src;
  int n, idx0;
  if (b < BE) { src = total_e; n = NE; idx0 = b * 256; }
  else        { src = total_n; n = NN; idx0 = (b - BE) * 256; }
  int t = threadIdx.x;
  int idx = idx0 + t;
  lds[t] = (idx < n) ? src[idx] : 0;
  for (int d = 128; d > 0; d >>= 1) {
    __syncthreads();
    if (t < d) lds[t] += lds[t + d];
  }
  if (t == 0) part[b] = lds[0];
}

__global__ void hg_scan2(int* __restrict__ part, int* __restrict__ off_e,
                         int* __restrict__ off_n) {
  __shared__ int lds[256];
  int t = threadIdx.x;
  int v = (t < BE) ? part[t] : 0;
  lds[t] = v;
  for (int d = 1; d < 256; d <<= 1) {
    __syncthreads();
    int u = (t >= d) ? lds[t - d] : 0;
    int w = lds[t];
    __syncthreads();
    lds[t] = u + w;
  }
  __syncthreads();
  if (t < BE) part[t] = lds[t] - v;
  if (t == 255) off_e[NE] = lds[255];
  __syncthreads();
  v = (t < BN) ? part[BE + t] : 0;
  lds[t] = v;
  for (int d = 1; d < 256; d <<= 1) {
    __syncthreads();
    int u = (t >= d) ? lds[t - d] : 0;
    int w = lds[t];
    __syncthreads();
    lds[t] = u + w;
  }
  __syncthreads();
  if (t < BN) part[BE + t] = lds[t] - v;
  if (t == 255) off_n[NN] = lds[255];
}

__global__ void hg_scan3(const int* __restrict__ total_e, const int* __restrict__ total_n,
                         const int* __restrict__ part,
                         int* __restrict__ off_e, int* __restrict__ off_n) {
  __shared__ int lds[256];
  int b = blockIdx.x;
  const int* src;
  int* dst;
  int n, idx0;
  if (b < BE) { src = total_e; dst = off_e; n = NE; idx0 = b * 256; }
  else        { src = total_n; dst = off_n; n = NN; idx0 = (b - BE) * 256; }
  int base = part[b];
  int t = threadIdx.x;
  int idx = idx0 + t;
  int v = (idx < n) ? src[idx] : 0;
  lds[t] = v;
  for (int d = 1; d < 256; d <<= 1) {
    __syncthreads();
    int u = (t >= d) ? lds[t - d] : 0;
    int w = lds[t];
    __syncthreads();
    lds[t] = u + w;
  }
  __syncthreads();
  if (idx < n) dst[idx] = base + lds[t] - v;
}

// ---- scatter: no atomics (slot = off + copy-prefix + rank) ------------------

__global__ void hg_scatter(const int* __restrict__ nidx, const int* __restrict__ eidx,
                           const unsigned* __restrict__ cntc,
                           const unsigned short* __restrict__ rank_e16,
                           const unsigned short* __restrict__ rank_n16,
                           const int* __restrict__ off_e, const int* __restrict__ off_n,
                           int* __restrict__ mem_e, int* __restrict__ mem_n) {
  int i = blockIdx.x * 256 + threadIdx.x;
  if (i >= NNZV) return;
  unsigned copy = (unsigned)i / EPB;
  int e = eidx[i];
  int n = nidx[i];
  unsigned be = cntc[(size_t)copy * HTC + (e >> 1)];
  be = (be >> ((e & 1) * 16)) & 0xffffu;
  unsigned bn = cntc[(size_t)copy * HTC + HEC + (n >> 1)];
  bn = (bn >> ((n & 1) * 16)) & 0xffffu;
  mem_e[off_e[e] + be + rank_e16[i]] = n;
  mem_n[off_n[n] + bn + rank_n16[i]] = e;
}

// ---- fused prep: Wt (transposed bf16) + x -> bf16 panel32 -------------------
// Xp layout: [8 panels][NN rows][32 cols]

__global__ void hg_prep(const float* __restrict__ W1, const float* __restrict__ W2,
                        __bf16* __restrict__ Wt1, __bf16* __restrict__ Wt2,
                        const float* __restrict__ X, __bf16* __restrict__ Xp) {
  int bid = blockIdx.x;
  if (bid < FD) {
    int id = bid * 256 + threadIdx.x;
    int n = id >> 8;
    int k = id & 255;
    Wt1[n * FD + k] = (__bf16)W1[k * FD + n];
    Wt2[n * FD + k] = (__bf16)W2[k * FD + n];
  } else {
    int idx = (bid - FD) * 256 + threadIdx.x;   // over NN*64 quads
    if (idx < NN * 64) {
      int r = idx >> 6;
      int c = (idx & 63) * 4;
      float4 v = *(const float4*)(X + (size_t)r * FD + c);
      bf16x4 o = {(__bf16)v.x, (__bf16)v.y, (__bf16)v.z, (__bf16)v.w};
      *(bf16x4*)(Xp + (size_t)(c >> 5) * NN * 32 + (size_t)r * 32 + (c & 31)) = o;
    }
  }
}

// ---- node -> edge aggregation: 8 chunk-passes over panel32 source -----------
// Wave per edge; 8 lanes per member (ushort4 = 32-col chunk row), 8 members
// lockstep, unroll x4. Source chunk (3.2 MB) is L2-resident per pass.

template<int APPLY>
__global__ __launch_bounds__(256) void
hg_agg_n2e_p(const __bf16* __restrict__ Xp, const int* __restrict__ off_e,
             const int* __restrict__ mem_e,
             const float* __restrict__ scale, const float* __restrict__ shift,
             __bf16* __restrict__ Ebf) {
  int wid = blockIdx.x * 4 + (threadIdx.x >> 6);   // edge id
  if (wid >= NE) return;
  int l = threadIdx.x & 63;
  int g = l >> 3;          // member sub-group 0..7
  int cq = l & 7;          // col-quad within 32-col chunk
  int lo = off_e[wid], hi = off_e[wid + 1];
  int cnt = hi - lo;
  float bi = cnt ? 1.0f / (float)cnt : 0.0f;
  const unsigned short* memu = (const unsigned short*)mem_e;  // unused cast guard
  (void)memu;
#pragma unroll 1
  for (int p = 0; p < 8; ++p) {
    int cbase = p * 32 + cq * 4;
    float4 sc = {0.f,0.f,0.f,0.f}, sh = {0.f,0.f,0.f,0.f};
    if (APPLY) {
      sc = *(const float4*)(scale + cbase);
      sh = *(const float4*)(shift + cbase);
    }
    const unsigned short* base = (const unsigned short*)Xp + (size_t)p * NN * 32 + cq * 4;
    float a0 = 0.f, a1 = 0.f, a2 = 0.f, a3 = 0.f;
#define N2E_ACC(v, live) do { \
      float f0 = b2f((v).x), f1 = b2f((v).y), f2 = b2f((v).z), f3 = b2f((v).w); \
      if (APPLY) { \
        f0 = fmaxf(fmaf(f0, sc.x, sh.x), 0.f); \
        f1 = fmaxf(fmaf(f1, sc.y, sh.y), 0.f); \
        f2 = fmaxf(fmaf(f2, sc.z, sh.z), 0.f); \
        f3 = fmaxf(fmaf(f3, sc.w, sh.w), 0.f); \
      } \
      if (live) { a0 += f0; a1 += f1; a2 += f2; a3 += f3; } } while (0)
    for (int m = lo; m < hi; m += 32) {
      int mA = m + g, mB = m + 8 + g, mC = m + 16 + g, mD = m + 24 + g;
      int iA = mem_e[min(mA, hi - 1)];
      int iB = mem_e[min(mB, hi - 1)];
      int iC = mem_e[min(mC, hi - 1)];
      int iD = mem_e[min(mD, hi - 1)];
      ushort4 vA = *(const ushort4*)(base + (size_t)iA * 32);
      ushort4 vB = *(const ushort4*)(base + (size_t)iB * 32);
      ushort4 vC = *(const ushort4*)(base + (size_t)iC * 32);
      ushort4 vD = *(const ushort4*)(base + (size_t)iD * 32);
      N2E_ACC(vA, mA < hi); N2E_ACC(vB, mB < hi);
      N2E_ACC(vC, mC < hi); N2E_ACC(vD, mD < hi);
    }
    // reduce across the 8 member-groups
    a0 += __shfl_xor(a0, 8);  a1 += __shfl_xor(a1, 8);
    a2 += __shfl_xor(a2, 8);  a3 += __shfl_xor(a3, 8);
    a0 += __shfl_xor(a0, 16); a1 += __shfl_xor(a1, 16);
    a2 += __shfl_xor(a2, 16); a3 += __shfl_xor(a3, 16);
    a0 += __shfl_xor(a0, 32); a1 += __shfl_xor(a1, 32);
    a2 += __shfl_xor(a2, 32); a3 += __shfl_xor(a3, 32);
    if (g == 0) {
      bf16x4 o = {(__bf16)(a0 * bi), (__bf16)(a1 * bi), (__bf16)(a2 * bi), (__bf16)(a3 * bi)};
      *(bf16x4*)(Ebf + (size_t)wid * FD + cbase) = o;   // E stays row-major for GEMM
    }
  }
}

// ---- GEMM: C = A[M x 256] @ Bt^T -> panel64 output [4][MPAD][64] ------------

__global__ __launch_bounds__(256) void
hg_gemm(const __bf16* __restrict__ A, const __bf16* __restrict__ Bt,
        __bf16* __restrict__ Cp, int Mrows) {
  int w = threadIdx.x >> 6, l = threadIdx.x & 63;
  int m0 = blockIdx.x * 64 + w * 16;
  int n0 = blockIdx.y * 64;
  int kb = (l >> 4) * 8;
  const bf16x8* Ap = (const bf16x8*)(A + (size_t)(m0 + (l & 15)) * FD + kb);
  const __bf16* Bbase = Bt + (size_t)(n0 + (l & 15)) * FD + kb;
  f32x4 acc0 = {0.f, 0.f, 0.f, 0.f}, acc1 = {0.f, 0.f, 0.f, 0.f};
  f32x4 acc2 = {0.f, 0.f, 0.f, 0.f}, acc3 = {0.f, 0.f, 0.f, 0.f};
#pragma unroll
  for (int ks = 0; ks < 8; ++ks) {
    bf16x8 a = Ap[ks * 4];
    bf16x8 b0 = *(const bf16x8*)(Bbase + (size_t)( 0) * FD + ks * 32);
    bf16x8 b1 = *(const bf16x8*)(Bbase + (size_t)(16) * FD + ks * 32);
    bf16x8 b2 = *(const bf16x8*)(Bbase + (size_t)(32) * FD + ks * 32);
    bf16x8 b3 = *(const bf16x8*)(Bbase + (size_t)(48) * FD + ks * 32);
    acc0 = __builtin_amdgcn_mfma_f32_16x16x32_bf16(a, b0, acc0, 0, 0, 0);
    acc1 = __builtin_amdgcn_mfma_f32_16x16x32_bf16(a, b1, acc1, 0, 0, 0);
    acc2 = __builtin_amdgcn_mfma_f32_16x16x32_bf16(a, b2, acc2, 0, 0, 0);
    acc3 = __builtin_amdgcn_mfma_f32_16x16x32_bf16(a, b3, acc3, 0, 0, 0);
  }
  int crow = m0 + (l >> 4) * 4;
  int lc = l & 15;                        // col within panel
  __bf16* P = Cp + (size_t)blockIdx.y * MPAD * 64;
#pragma unroll
  for (int r = 0; r < 4; ++r) {
    int rr = crow + r;
    if (rr < Mrows) {
      P[(size_t)rr * 64 + lc +  0] = (__bf16)acc0[r];
      P[(size_t)rr * 64 + lc + 16] = (__bf16)acc1[r];
      P[(size_t)rr * 64 + lc + 32] = (__bf16)acc2[r];
      P[(size_t)rr * 64 + lc + 48] = (__bf16)acc3[r];
    }
  }
}

// ---- edge -> node aggregation: 4 chunk-passes over eW panel64 ---------------
// Wave per node; 16 lanes per member (ushort4 = 64-col chunk row), 4 members
// lockstep, unroll x4. Chunk (2.5 MB) is L2-resident. Output panel32.

__global__ __launch_bounds__(256) void
hg_agg_e2n_p(const __bf16* __restrict__ eWp, const int* __restrict__ off_n,
             const int* __restrict__ mem_n, const float* __restrict__ wedge,
             const float* __restrict__ bias, __bf16* __restrict__ Outp) {
  int node = blockIdx.x * 4 + (threadIdx.x >> 6);
  if (node >= NN) return;
  int l = threadIdx.x & 63;
  int g = l >> 4;          // member sub-group 0..3
  int cq = l & 15;         // col-quad within 64-col chunk
  int lo = off_n[node], hi = off_n[node + 1];
  float di = 0.f;
#pragma unroll 1
  for (int p = 0; p < 4; ++p) {
    const unsigned short* base = (const unsigned short*)eWp + (size_t)p * MPAD * 64 + cq * 4;
    float a0 = 0.f, a1 = 0.f, a2 = 0.f, a3 = 0.f;
    float dw = 0.f;
    for (int m = lo; m < hi; m += 16) {
      int mA = m + g, mB = m + 4 + g, mC = m + 8 + g, mD = m + 12 + g;
      int iA = mem_n[min(mA, hi - 1)];
      int iB = mem_n[min(mB, hi - 1)];
      int iC = mem_n[min(mC, hi - 1)];
      int iD = mem_n[min(mD, hi - 1)];
      ushort4 vA = *(const ushort4*)(base + (size_t)iA * 64);
      ushort4 vB = *(const ushort4*)(base + (size_t)iB * 64);
      ushort4 vC = *(const ushort4*)(base + (size_t)iC * 64);
      ushort4 vD = *(const ushort4*)(base + (size_t)iD * 64);
      if (p == 0 && cq == 0) {
        if (mA < hi) dw += wedge[iA];
        if (mB < hi) dw += wedge[iB];
        if (mC < hi) dw += wedge[iC];
        if (mD < hi) dw += wedge[iD];
      }
      if (mA < hi) { a0 += b2f(vA.x); a1 += b2f(vA.y); a2 += b2f(vA.z); a3 += b2f(vA.w); }
      if (mB < hi) { a0 += b2f(vB.x); a1 += b2f(vB.y); a2 += b2f(vB.z); a3 += b2f(vB.w); }
      if (mC < hi) { a0 += b2f(vC.x); a1 += b2f(vC.y); a2 += b2f(vC.z); a3 += b2f(vC.w); }
      if (mD < hi) { a0 += b2f(vD.x); a1 += b2f(vD.y); a2 += b2f(vD.z); a3 += b2f(vD.w); }
    }
    a0 += __shfl_xor(a0, 16); a1 += __shfl_xor(a1, 16);
    a2 += __shfl_xor(a2, 16); a3 += __shfl_xor(a3, 16);
    a0 += __shfl_xor(a0, 32); a1 += __shfl_xor(a1, 32);
    a2 += __shfl_xor(a2, 32); a3 += __shfl_xor(a3, 32);
    if (p == 0) {
      dw += __shfl_xor(dw, 16);
      dw += __shfl_xor(dw, 32);
      dw = __shfl(dw, (threadIdx.x & 192));     // lane 0 of this wave
      di = (dw != 0.f) ? 1.0f / dw : 0.0f;
    }
    if (g == 0) {
      int cbase = p * 64 + cq * 4;              // global col
      float4 b4 = *(const float4*)(bias + cbase);
      bf16x4 o = {(__bf16)fmaf(a0, di, b4.x), (__bf16)fmaf(a1, di, b4.y),
                  (__bf16)fmaf(a2, di, b4.z), (__bf16)fmaf(a3, di, b4.w)};
      *(bf16x4*)(Outp + (size_t)(cbase >> 5) * NN * 32 + (size_t)node * 32 + (cbase & 31)) = o;
    }
  }
}

// ---- column stats over Outp panel32 (sum, sumsq) ----------------------------

__global__ __launch_bounds__(256) void
hg_stats(const __bf16* __restrict__ Outp, float* __restrict__ stats) {
  int t = threadIdx.x;
  int pnl = t >> 5, cc = t & 31;
  int c = pnl * 32 + cc;
  int rpb = (NN + gridDim.x - 1) / gridDim.x;
  int r0 = blockIdx.x * rpb;
  int r1 = r0 + rpb;
  if (r1 > NN) r1 = NN;
  const unsigned short* Ou = (const unsigned short*)Outp + (size_t)pnl * NN * 32 + cc;
  float s = 0.f, q = 0.f;
  for (int r = r0; r < r1; ++r) {
    float v = b2f(Ou[(size_t)r * 32]);
    s += v;
    q = fmaf(v, v, q);
  }
  atomicAdd(&stats[c], s);
  atomicAdd(&stats[FD + c], q);
}

// ---- BN finalize + final fused apply/ReLU -----------------------------------

__global__ void hg_bn_finalize(const float* __restrict__ stats, const float* __restrict__ g,
                               const float* __restrict__ be,
                               float* __restrict__ scale, float* __restrict__ shift) {
  int c = threadIdx.x;
  float mu = stats[c] * (1.0f / NN);
  float var = stats[FD + c] * (1.0f / NN) - mu * mu;
  float sc = g[c] * rsqrtf(var + EPSV);
  scale[c] = sc;
  shift[c] = fmaf(-mu, sc, be[c]);
}

__global__ void hg_apply_bf(const __bf16* __restrict__ Outp, const float* __restrict__ scale,
                            const float* __restrict__ shift, float* __restrict__ H) {
  int idx = blockIdx.x * 256 + threadIdx.x;   // over NN*64 quads
  if (idx >= NN * 64) return;
  int r = idx >> 6;
  int c = (idx & 63) * 4;
  ushort4 v = *(const ushort4*)((const unsigned short*)Outp
               + (size_t)(c >> 5) * NN * 32 + (size_t)r * 32 + (c & 31));
  float4 sa = *(const float4*)(scale + c);
  float4 ha = *(const float4*)(shift + c);
  float4 o;
  o.x = fmaxf(fmaf(b2f(v.x), sa.x, ha.x), 0.f);
  o.y = fmaxf(fmaf(b2f(v.y), sa.y, ha.y), 0.f);
  o.z = fmaxf(fmaf(b2f(v.z), sa.z, ha.z), 0.f);
  o.w = fmaxf(fmaf(b2f(v.w), sa.w, ha.w), 0.f);
  *(float4*)(H + (size_t)r * FD + c) = o;
}

// ---- launch -----------------------------------------------------------------

extern "C" void kernel_launch(void* const* d_in, const int* in_sizes, int n_in,
                              void* d_out, int out_size, void* d_ws, size_t ws_size,
                              hipStream_t stream) {
  const float* x    = (const float*)d_in[0];
  const int*   hei  = (const int*)d_in[1];
  const int*   nidx = hei;               // hyperedge_index[0]
  const int*   eidx = hei + NNZV;        // hyperedge_index[1]
  const float* wedge = (const float*)d_in[2];
  const float* W1  = (const float*)d_in[3];
  const float* b1  = (const float*)d_in[4];
  const float* g1  = (const float*)d_in[5];
  const float* be1 = (const float*)d_in[6];
  const float* W2  = (const float*)d_in[7];
  const float* b2  = (const float*)d_in[8];
  const float* g2  = (const float*)d_in[9];
  const float* be2 = (const float*)d_in[10];
  float* out = (float*)d_out;

  char* base = (char*)d_ws;
  size_t cur = 0;
  auto alloc = [&](size_t bytes) -> void* {
    void* p = base + cur;
    cur += (bytes + 255) & ~(size_t)255;
    return p;
  };
  unsigned* cntc = (unsigned*)alloc((size_t)NCPY * HTC * 4);   // 17.9 MB
  unsigned short* rank_e16 = (unsigned short*)alloc((size_t)NNZV * 2);
  unsigned short* rank_n16 = (unsigned short*)alloc((size_t)NNZV * 2);
  int*   total_e = (int*)alloc(NE * 4);
  int*   total_n = (int*)alloc(NN * 4);
  int*   part  = (int*)alloc((BE + BN) * 4);
  int*   off_e = (int*)alloc((NE + 1) * 4);
  int*   off_n = (int*)alloc((NN + 1) * 4);
  int*   mem_e = (int*)alloc((size_t)NNZV * 4);
  int*   mem_n = (int*)alloc((size_t)NNZV * 4);
  __bf16* Wt1  = (__bf16*)alloc(FD * FD * 2);
  __bf16* Wt2  = (__bf16*)alloc(FD * FD * 2);
  __bf16* Xp   = (__bf16*)alloc((size_t)NN * FD * 2);     // panel32
  __bf16* Ebf  = (__bf16*)alloc((size_t)MPAD * FD * 2);   // row-major
  __bf16* eWp  = (__bf16*)alloc((size_t)MPAD * FD * 2);   // panel64
  __bf16* Outp = (__bf16*)alloc((size_t)NN * FD * 2);     // panel32
  float* stats = (float*)alloc(2 * FD * 4);
  float* scale1 = (float*)alloc(FD * 4);
  float* shift1 = (float*)alloc(FD * 4);
  float* scale2 = (float*)alloc(FD * 4);
  float* shift2 = (float*)alloc(FD * 4);
  if (cur > ws_size) return;

  // CSR build (no global atomics anywhere)
  hg_histlds<<<NCPY, 256, 0, stream>>>(nidx, eidx, cntc, rank_e16, rank_n16);
  hg_colreduce<<<(HTC + 255) / 256, 256, 0, stream>>>(cntc, total_e, total_n);
  hg_scan1<<<BE + BN, 256, 0, stream>>>(total_e, total_n, part);
  hg_scan2<<<1, 256, 0, stream>>>(part, off_e, off_n);
  hg_scan3<<<BE + BN, 256, 0, stream>>>(total_e, total_n, part, off_e, off_n);
  hg_scatter<<<(NNZV + 255) / 256, 256, 0, stream>>>(nidx, eidx, cntc, rank_e16, rank_n16,
                                                     off_e, off_n, mem_e, mem_n);
  hg_prep<<<FD + (NN * 64 + 255) / 256, 256, 0, stream>>>(W1, W2, Wt1, Wt2, x, Xp);

  const int N2E_BLOCKS = (NE + 3) / 4;     // wave per edge
  const int E2N_BLOCKS = (NN + 3) / 4;     // wave per node
  const dim3 GEMM_GRID(MPAD / 64, 4);

  // ---- layer 1
  hg_agg_n2e_p<0><<<N2E_BLOCKS, 256, 0, stream>>>(Xp, off_e, mem_e, nullptr, nullptr, Ebf);
  hg_gemm<<<GEMM_GRID, 256, 0, stream>>>(Ebf, Wt1, eWp, NE);
  hg_agg_e2n_p<<<E2N_BLOCKS, 256, 0, stream>>>(eWp, off_n, mem_n, wedge, b1, Outp);
  hipMemsetAsync(stats, 0, 2 * FD * 4, stream);
  hg_stats<<<256, 256, 0, stream>>>(Outp, stats);
  hg_bn_finalize<<<1, FD, 0, stream>>>(stats, g1, be1, scale1, shift1);

  // ---- layer 2 (BN1+ReLU fused into the gather)
  hg_agg_n2e_p<1><<<N2E_BLOCKS, 256, 0, stream>>>(Outp, off_e, mem_e, scale1, shift1, Ebf);
  hg_gemm<<<GEMM_GRID, 256, 0, stream>>>(Ebf, Wt2, eWp, NE);
  hg_agg_e2n_p<<<E2N_BLOCKS, 256, 0, stream>>>(eWp, off_n, mem_n, wedge, b2, Outp);
  hipMemsetAsync(stats, 0, 2 * FD * 4, stream);
  hg_stats<<<256, 256, 0, stream>>>(Outp, stats);
  hg_bn_finalize<<<1, FD, 0, stream>>>(stats, g2, be2, scale2, shift2);
  hg_apply_bf<<<(NN * 64 + 255) / 256, 256, 0, stream>>>(Outp, scale2, shift2, out);
}